// Round 1
// baseline (167.814 us; speedup 1.0000x reference)
//
#include <hip/hip_runtime.h>
#include <hip/hip_bf16.h>
#include <math.h>

// Problem constants
#define BB 64
#define SS 2048
#define HH 1024
#define EE 1024
#define DD 64          // window half-size
#define G4H 4096       // 4*H
#define KS1 6          // k-splits for gates GEMM (K=3072)
#define KS2 4          // k-splits for H=1024 GEMMs

__device__ __forceinline__ float sigmoidf_(float x) { return 1.0f / (1.0f + expf(-x)); }

// Generic partial GEMM: part[ks][j][b] = sum_{k in chunk ks} Xrow(b,k) * Wrow(j,k)
// Xrow(b,k) = k < k1len ? X1[b*x1ld+k] : X2[b*x2ld + (k-k1len)]
// Wrow(j,k) = k < k1len ? W1[j*w1ld+k] : W2[j*w2ld + (k-k1len)]
// grid = (Jtot/64, KS), block = 256. B fixed at 64.
__global__ __launch_bounds__(256) void gemm_part(
    const float* __restrict__ X1, int x1ld,
    const float* __restrict__ X2, int x2ld,
    const float* __restrict__ W1, int w1ld,
    const float* __restrict__ W2, int w2ld,
    int k1len, int Ktot, int Jtot,
    float* __restrict__ part)
{
    const int jt = blockIdx.x;
    const int ks = blockIdx.y;
    const int KS = gridDim.y;
    const int kchunk = Ktot / KS;
    const int k0 = ks * kchunk;
    const int t  = threadIdx.x;
    const int bl = t & 63;       // batch lane
    const int jq = t >> 6;       // 0..3 -> owns 16 j's

    __shared__ float Xs[64][65];
    __shared__ float Ws[64][65];

    float acc[16];
#pragma unroll
    for (int i = 0; i < 16; ++i) acc[i] = 0.0f;

    const int c4 = (t & 15) * 4;   // col within 64-wide k tile
    const int r0 = t >> 4;         // 0..15

    for (int kk = k0; kk < k0 + kchunk; kk += 64) {
        const int kg = kk + c4;
#pragma unroll
        for (int i = 0; i < 4; ++i) {
            const int row = r0 + i * 16;   // 0..63
            const float* xs = (kg < k1len) ? (X1 + (size_t)row * x1ld + kg)
                                           : (X2 + (size_t)row * x2ld + (kg - k1len));
            float4 xv = *(const float4*)xs;
            Xs[row][c4 + 0] = xv.x; Xs[row][c4 + 1] = xv.y;
            Xs[row][c4 + 2] = xv.z; Xs[row][c4 + 3] = xv.w;

            const int j = jt * 64 + row;
            const float* wsrc = (kg < k1len) ? (W1 + (size_t)j * w1ld + kg)
                                             : (W2 + (size_t)j * w2ld + (kg - k1len));
            float4 wv = *(const float4*)wsrc;
            Ws[row][c4 + 0] = wv.x; Ws[row][c4 + 1] = wv.y;
            Ws[row][c4 + 2] = wv.z; Ws[row][c4 + 3] = wv.w;
        }
        __syncthreads();

#pragma unroll 8
        for (int k = 0; k < 64; ++k) {
            const float xv = Xs[bl][k];
#pragma unroll
            for (int jj = 0; jj < 16; ++jj)
                acc[jj] = fmaf(Ws[jq * 16 + jj][k], xv, acc[jj]);
        }
        __syncthreads();
    }

#pragma unroll
    for (int jj = 0; jj < 16; ++jj) {
        const int j = jt * 64 + jq * 16 + jj;
        part[((size_t)ks * Jtot + j) * BB + bl] = acc[jj];
    }
}

// LSTM cell from gate partials. grid = H/4 = 256 blocks, block = 256.
__global__ __launch_bounds__(256) void lstm_cell(
    const float* __restrict__ part,
    const float* __restrict__ b_ih, const float* __restrict__ b_hh,
    const float* __restrict__ c0, float* __restrict__ yt)
{
    const int t = threadIdx.x;
    const int b = t & 63;
    const int h = blockIdx.x * 4 + (t >> 6);

    float g4[4];
#pragma unroll
    for (int q = 0; q < 4; ++q) {
        const int j = h + q * HH;
        float s = b_ih[j] + b_hh[j];
#pragma unroll
        for (int ks = 0; ks < KS1; ++ks)
            s += part[((size_t)ks * G4H + j) * BB + b];
        g4[q] = s;
    }
    const float ig = sigmoidf_(g4[0]);
    const float fg = sigmoidf_(g4[1]);
    const float gg = tanhf(g4[2]);
    const float og = sigmoidf_(g4[3]);
    const float c  = fg * c0[(size_t)b * HH + h] + ig * gg;
    yt[(size_t)b * HH + h] = og * tanhf(c);
}

// p_t = len * sigmoid( sum_i tanh(t1[b][i]) * v[i] ); window bounds.
// grid = B, block = 256. part2[ks][i][b]
__global__ __launch_bounds__(256) void pos_kernel(
    const float* __restrict__ part2, const float* __restrict__ v,
    const int* __restrict__ elen,
    float* __restrict__ p_out, int* __restrict__ lr_out)
{
    const int b = blockIdx.x;
    const int t = threadIdx.x;
    float acc = 0.0f;
    for (int i = t; i < HH; i += 256) {
        float s = 0.0f;
#pragma unroll
        for (int ks = 0; ks < KS2; ++ks)
            s += part2[((size_t)ks * HH + i) * BB + b];
        acc += tanhf(s) * v[i];
    }
    __shared__ float red[256];
    red[t] = acc;
    __syncthreads();
    if (t < 128) red[t] += red[t + 128];
    __syncthreads();
    if (t < 64) {
        float x = red[t] + red[t + 64];
#pragma unroll
        for (int off = 32; off; off >>= 1) x += __shfl_xor(x, off);
        if (t == 0) {
            const float pt  = sigmoidf_(x);
            const float len = (float)elen[b];
            const float p   = len * pt;
            const int   pf  = (int)floorf(p);
            const int   left  = max(0, pf - DD);
            const int   right = min(elen[b], pf + DD);
            p_out[b] = p;
            lr_out[b * 2 + 0] = left;
            lr_out[b * 2 + 1] = right;
        }
    }
}

// Windowed scores + softmax + gaussian weight -> at[b][0..128)
// grid = B, block = 512 (8 waves).
__global__ __launch_bounds__(512) void attn_scores(
    const float* __restrict__ encode_h, const float* __restrict__ yt,
    const float* __restrict__ p_buf, const int* __restrict__ lr,
    float* __restrict__ at_out)
{
    const int b = blockIdx.x;
    const int t = threadIdx.x;
    const int lane = t & 63;
    const int wv = t >> 6;

    __shared__ float yts[HH];
    __shared__ float sc[2 * DD];
    __shared__ float m_sh, sum_sh;

    for (int i = t; i < HH; i += 512) yts[i] = yt[(size_t)b * HH + i];
    const int left = lr[b * 2], right = lr[b * 2 + 1];
    const int wsize = right - left;
    __syncthreads();

    for (int si = wv; si < wsize; si += 8) {
        const float* eh = encode_h + ((size_t)b * SS + (left + si)) * HH;
        float s = 0.0f;
#pragma unroll
        for (int c = 0; c < 4; ++c) {
            const int hb = c * 256 + lane * 4;
            float4 e = *(const float4*)(eh + hb);
            s += e.x * yts[hb] + e.y * yts[hb + 1] + e.z * yts[hb + 2] + e.w * yts[hb + 3];
        }
#pragma unroll
        for (int off = 32; off; off >>= 1) s += __shfl_xor(s, off);
        if (lane == 0) sc[si] = s;
    }
    __syncthreads();

    if (t < 64) {
        float m = -1e30f;
        for (int si = lane; si < wsize; si += 64) m = fmaxf(m, sc[si]);
#pragma unroll
        for (int off = 32; off; off >>= 1) m = fmaxf(m, __shfl_xor(m, off));
        float ssum = 0.0f;
        for (int si = lane; si < wsize; si += 64) ssum += expf(sc[si] - m);
#pragma unroll
        for (int off = 32; off; off >>= 1) ssum += __shfl_xor(ssum, off);
        if (lane == 0) { m_sh = m; sum_sh = ssum; }
    }
    __syncthreads();

    const float m = m_sh;
    const float inv = 1.0f / sum_sh;
    const float p = p_buf[b];
    for (int si = t; si < 2 * DD; si += 512) {
        float a = 0.0f;
        if (si < wsize) {
            const float dj = (float)(left + si) - p;
            a = expf(sc[si] - m) * inv * expf(-(dj * dj) * (1.0f / 2048.0f));
        }
        at_out[b * 2 * DD + si] = a;
    }
}

// ct[b][h] = sum_si at[si] * encode_h[b][left+si][h].  grid = (B, 4), block = 256.
__global__ __launch_bounds__(256) void attn_ct(
    const float* __restrict__ encode_h, const float* __restrict__ at,
    const int* __restrict__ lr, float* __restrict__ ct)
{
    const int b = blockIdx.x;
    const int h = blockIdx.y * 256 + threadIdx.x;
    const int left = lr[b * 2];
    const int wsize = lr[b * 2 + 1] - left;

    __shared__ float ats[2 * DD];
    if (threadIdx.x < 2 * DD) ats[threadIdx.x] = at[b * 2 * DD + threadIdx.x];
    __syncthreads();

    const float* ehb = encode_h + ((size_t)b * SS + left) * HH + h;
    float acc = 0.0f;
    for (int si = 0; si < wsize; ++si)
        acc = fmaf(ats[si], ehb[(size_t)si * HH], acc);
    ct[(size_t)b * HH + h] = acc;
}

// out[b][j] = sum_ks part3[ks][j][b].  grid = B, block = 256.
__global__ __launch_bounds__(256) void reduce_out(
    const float* __restrict__ part3, float* __restrict__ out)
{
    const int b = blockIdx.x;
    for (int j = threadIdx.x; j < HH; j += 256) {
        float s = 0.0f;
#pragma unroll
        for (int ks = 0; ks < KS2; ++ks)
            s += part3[((size_t)ks * HH + j) * BB + b];
        out[(size_t)b * HH + j] = s;
    }
}

extern "C" void kernel_launch(void* const* d_in, const int* in_sizes, int n_in,
                              void* d_out, int out_size, void* d_ws, size_t ws_size,
                              hipStream_t stream)
{
    const float* encode_h = (const float*)d_in[0];
    const float* x_t      = (const float*)d_in[1];
    const float* h0       = (const float*)d_in[2];
    const float* c0       = (const float*)d_in[3];
    const float* W_ih     = (const float*)d_in[4];
    const float* W_hh     = (const float*)d_in[5];
    const float* b_ih     = (const float*)d_in[6];
    const float* b_hh     = (const float*)d_in[7];
    const float* W_ht2tan = (const float*)d_in[8];
    const float* W_tan2pt = (const float*)d_in[9];
    const float* W_ct2ht  = (const float*)d_in[10];
    const int*   elen     = (const int*)d_in[11];
    float* out = (float*)d_out;

    float* ws = (float*)d_ws;
    float* gates_part = ws;                                   // KS1*4096*64
    float* yt    = gates_part + (size_t)KS1 * G4H * BB;       // 65536
    float* part2 = yt + (size_t)BB * HH;                      // KS2*1024*64
    float* pbuf  = part2 + (size_t)KS2 * HH * BB;             // 64
    int*   lrbuf = (int*)(pbuf + BB);                         // 128 ints
    float* atbuf = pbuf + BB + 2 * BB;                        // 64*128
    float* ctbuf = atbuf + (size_t)BB * 2 * DD;               // 65536
    float* part3 = ctbuf + (size_t)BB * HH;                   // KS2*1024*64

    // K1: gates partial GEMM  (K = 2048 | 1024 concat)
    dim3 g1(G4H / 64, KS1);
    gemm_part<<<g1, 256, 0, stream>>>(x_t, EE + HH, h0, HH,
                                      W_ih, EE + HH, W_hh, HH,
                                      2048, 3072, G4H, gates_part);
    // K2: LSTM cell -> yt
    lstm_cell<<<HH / 4, 256, 0, stream>>>(gates_part, b_ih, b_hh, c0, yt);

    // K3a: t1 = yt @ W_ht2tan^T (partials)
    dim3 g3(HH / 64, KS2);
    gemm_part<<<g3, 256, 0, stream>>>(yt, HH, yt, HH,
                                      W_ht2tan, HH, W_ht2tan, HH,
                                      HH, HH, HH, part2);
    // K3b: p, window bounds
    pos_kernel<<<BB, 256, 0, stream>>>(part2, W_tan2pt, elen, pbuf, lrbuf);

    // K4a: windowed scores + softmax + gauss -> at
    attn_scores<<<BB, 512, 0, stream>>>(encode_h, yt, pbuf, lrbuf, atbuf);
    // K4b: ct
    dim3 g4(BB, 4);
    attn_ct<<<g4, 256, 0, stream>>>(encode_h, atbuf, lrbuf, ctbuf);

    // K5: ht partials = ct @ W_ct2ht^T
    gemm_part<<<g3, 256, 0, stream>>>(ctbuf, HH, ctbuf, HH,
                                      W_ct2ht, HH, W_ct2ht, HH,
                                      HH, HH, HH, part3);
    // K6: reduce -> out
    reduce_out<<<BB, 256, 0, stream>>>(part3, out);
}

// Round 2
// 114.163 us; speedup vs baseline: 1.4699x; 1.4699x over previous
//
#include <hip/hip_runtime.h>
#include <hip/hip_bf16.h>
#include <math.h>

// Problem constants
#define BB 64
#define SS 2048
#define HH 1024
#define EE 1024
#define DD 64          // window half-size
#define G4H 4096       // 4*H
#define KS1 8          // k-splits for gates GEMM (K=3072, kchunk=384)
#define KS2 16         // k-splits for H=1024 GEMMs (kchunk=64)

__device__ __forceinline__ float sigmoidf_(float x) { return 1.0f / (1.0f + expf(-x)); }

// Register-tiled partial GEMM: part[ks][j][b] = sum_{k in chunk} Xrow(b,k)*Wrow(j,k)
// X/W are each a concat of two row-major matrices along k (split at k1len).
// Tile: 128 j x 64 b x 64 k. Thread owns acc[4 b][8 j]. grid=(Jtot/128, KS), block=256.
__global__ __launch_bounds__(256) void gemm_part(
    const float* __restrict__ X1, int x1ld,
    const float* __restrict__ X2, int x2ld,
    const float* __restrict__ W1, int w1ld,
    const float* __restrict__ W2, int w2ld,
    int k1len, int Ktot, int Jtot,
    float* __restrict__ part)
{
    const int jt = blockIdx.x;        // j-tile of 128
    const int ks = blockIdx.y;
    const int KS = gridDim.y;
    const int kchunk = Ktot / KS;     // multiple of 64
    const int k0 = ks * kchunk;
    const int t  = threadIdx.x;

    // compute-phase mapping: b = tb + 16*bb, j = tj + 16*jj
    const int tb = t & 15;
    const int tj = t >> 4;            // 0..15

    // staging mapping: k-col group c (4 floats), row r
    const int c = t & 15;
    const int r = t >> 4;             // 0..15

    __shared__ float Xs[64][68];      // [b][k] pad->row stride 272B (16B aligned)
    __shared__ float Ws[128][68];     // [j][k]

    float acc[4][8];
#pragma unroll
    for (int bb = 0; bb < 4; ++bb)
#pragma unroll
        for (int jj = 0; jj < 8; ++jj) acc[bb][jj] = 0.0f;

    for (int kk = k0; kk < k0 + kchunk; kk += 64) {
        const int kg = kk + 4 * c;
        // stage X tile: 64 rows
#pragma unroll
        for (int i = 0; i < 4; ++i) {
            const int b = r + 16 * i;
            const float* xs = (kg < k1len) ? (X1 + (size_t)b * x1ld + kg)
                                           : (X2 + (size_t)b * x2ld + (kg - k1len));
            *(float4*)&Xs[b][4 * c] = *(const float4*)xs;
        }
        // stage W tile: 128 rows
#pragma unroll
        for (int i = 0; i < 8; ++i) {
            const int jr = r + 16 * i;
            const int j  = jt * 128 + jr;
            const float* wsrc = (kg < k1len) ? (W1 + (size_t)j * w1ld + kg)
                                             : (W2 + (size_t)j * w2ld + (kg - k1len));
            *(float4*)&Ws[jr][4 * c] = *(const float4*)wsrc;
        }
        __syncthreads();

#pragma unroll 4
        for (int k4 = 0; k4 < 64; k4 += 4) {
            float4 xv[4], wv[8];
#pragma unroll
            for (int bb = 0; bb < 4; ++bb)
                xv[bb] = *(const float4*)&Xs[tb + 16 * bb][k4];
#pragma unroll
            for (int jj = 0; jj < 8; ++jj)
                wv[jj] = *(const float4*)&Ws[tj + 16 * jj][k4];
#pragma unroll
            for (int bb = 0; bb < 4; ++bb)
#pragma unroll
                for (int jj = 0; jj < 8; ++jj) {
                    acc[bb][jj] = fmaf(xv[bb].x, wv[jj].x, acc[bb][jj]);
                    acc[bb][jj] = fmaf(xv[bb].y, wv[jj].y, acc[bb][jj]);
                    acc[bb][jj] = fmaf(xv[bb].z, wv[jj].z, acc[bb][jj]);
                    acc[bb][jj] = fmaf(xv[bb].w, wv[jj].w, acc[bb][jj]);
                }
        }
        __syncthreads();
    }

    // write partials: part[(ks*Jtot + j)*64 + b]
#pragma unroll
    for (int jj = 0; jj < 8; ++jj) {
        const int j = jt * 128 + tj + 16 * jj;
#pragma unroll
        for (int bb = 0; bb < 4; ++bb)
            part[((size_t)ks * Jtot + j) * BB + (tb + 16 * bb)] = acc[bb][jj];
    }
}

// LSTM cell from gate partials. grid = H/4 = 256 blocks, block = 256.
__global__ __launch_bounds__(256) void lstm_cell(
    const float* __restrict__ part,
    const float* __restrict__ b_ih, const float* __restrict__ b_hh,
    const float* __restrict__ c0, float* __restrict__ yt)
{
    const int t = threadIdx.x;
    const int b = t & 63;
    const int h = blockIdx.x * 4 + (t >> 6);

    float g4[4];
#pragma unroll
    for (int q = 0; q < 4; ++q) {
        const int j = h + q * HH;
        float s = b_ih[j] + b_hh[j];
#pragma unroll
        for (int ks = 0; ks < KS1; ++ks)
            s += part[((size_t)ks * G4H + j) * BB + b];
        g4[q] = s;
    }
    const float ig = sigmoidf_(g4[0]);
    const float fg = sigmoidf_(g4[1]);
    const float gg = tanhf(g4[2]);
    const float og = sigmoidf_(g4[3]);
    const float c  = fg * c0[(size_t)b * HH + h] + ig * gg;
    yt[(size_t)b * HH + h] = og * tanhf(c);
}

// p_t = len * sigmoid( sum_i tanh(t1[b][i]) * v[i] ); window bounds.
// grid = B, block = 256. part2[ks][i][b]
__global__ __launch_bounds__(256) void pos_kernel(
    const float* __restrict__ part2, const float* __restrict__ v,
    const int* __restrict__ elen,
    float* __restrict__ p_out, int* __restrict__ lr_out)
{
    const int b = blockIdx.x;
    const int t = threadIdx.x;
    float acc = 0.0f;
    for (int i = t; i < HH; i += 256) {
        float s = 0.0f;
#pragma unroll
        for (int ks = 0; ks < KS2; ++ks)
            s += part2[((size_t)ks * HH + i) * BB + b];
        acc += tanhf(s) * v[i];
    }
    __shared__ float red[256];
    red[t] = acc;
    __syncthreads();
    if (t < 128) red[t] += red[t + 128];
    __syncthreads();
    if (t < 64) {
        float x = red[t] + red[t + 64];
#pragma unroll
        for (int off = 32; off; off >>= 1) x += __shfl_xor(x, off);
        if (t == 0) {
            const float pt  = sigmoidf_(x);
            const float len = (float)elen[b];
            const float p   = len * pt;
            const int   pf  = (int)floorf(p);
            const int   left  = max(0, pf - DD);
            const int   right = min(elen[b], pf + DD);
            p_out[b] = p;
            lr_out[b * 2 + 0] = left;
            lr_out[b * 2 + 1] = right;
        }
    }
}

// Windowed raw scores. grid = (B, 4), block = 256 (4 waves, 8 si each).
// Writes sc[b][0..128) with -1e30 padding beyond window.
__global__ __launch_bounds__(256) void attn_scores(
    const float* __restrict__ encode_h, const float* __restrict__ yt,
    const int* __restrict__ lr, float* __restrict__ sc_out)
{
    const int b = blockIdx.x;
    const int q = blockIdx.y;
    const int t = threadIdx.x;
    const int lane = t & 63;
    const int wv = t >> 6;

    __shared__ float yts[HH];
    *(float4*)&yts[t * 4] = *(const float4*)&yt[(size_t)b * HH + t * 4];
    const int left = lr[b * 2], right = lr[b * 2 + 1];
    const int wsize = right - left;
    __syncthreads();

#pragma unroll
    for (int rr = 0; rr < 8; ++rr) {
        const int si = q * 32 + wv * 8 + rr;
        float s = -1e30f;
        if (si < wsize) {
            const float* eh = encode_h + ((size_t)b * SS + (left + si)) * HH;
            s = 0.0f;
#pragma unroll
            for (int cc = 0; cc < 4; ++cc) {
                const int hb = cc * 256 + lane * 4;
                float4 e = *(const float4*)(eh + hb);
                s += e.x * yts[hb] + e.y * yts[hb + 1] + e.z * yts[hb + 2] + e.w * yts[hb + 3];
            }
#pragma unroll
            for (int off = 32; off; off >>= 1) s += __shfl_xor(s, off);
        }
        if (lane == 0) sc_out[b * 2 * DD + si] = s;
    }
}

// Fused softmax+gauss+ct: grid = (B, 4), block = 256 (h chunk of 256).
__global__ __launch_bounds__(256) void attn_ct(
    const float* __restrict__ encode_h, const float* __restrict__ sc,
    const float* __restrict__ p_buf, const int* __restrict__ lr,
    float* __restrict__ ct)
{
    const int b = blockIdx.x;
    const int t = threadIdx.x;
    const int lane = t & 63;
    const int h = blockIdx.y * 256 + t;

    __shared__ float scs[2 * DD];
    __shared__ float ats[2 * DD];

    const int left = lr[b * 2];
    if (t < 2 * DD) scs[t] = sc[b * 2 * DD + t];
    __syncthreads();

    // per-wave redundant softmax stats over 128 values
    float m = fmaxf(scs[lane], scs[lane + 64]);
#pragma unroll
    for (int off = 32; off; off >>= 1) m = fmaxf(m, __shfl_xor(m, off));
    float ssum = expf(scs[lane] - m) + expf(scs[lane + 64] - m);
#pragma unroll
    for (int off = 32; off; off >>= 1) ssum += __shfl_xor(ssum, off);
    const float inv = 1.0f / ssum;

    if (t < 2 * DD) {
        const float dj = (float)(left + t) - p_buf[b];
        ats[t] = expf(scs[t] - m) * inv * expf(-(dj * dj) * (1.0f / 2048.0f));
    }
    __syncthreads();

    const float* ehb = encode_h + ((size_t)b * SS + left) * HH + h;
    float a0 = 0.0f, a1 = 0.0f, a2 = 0.0f, a3 = 0.0f;
#pragma unroll 4
    for (int si = 0; si < 2 * DD; si += 4) {
        a0 = fmaf(ats[si + 0], ehb[(size_t)(si + 0) * HH], a0);
        a1 = fmaf(ats[si + 1], ehb[(size_t)(si + 1) * HH], a1);
        a2 = fmaf(ats[si + 2], ehb[(size_t)(si + 2) * HH], a2);
        a3 = fmaf(ats[si + 3], ehb[(size_t)(si + 3) * HH], a3);
    }
    ct[(size_t)b * HH + h] = (a0 + a1) + (a2 + a3);
}

// out[b][j] = sum_ks part3[ks][j][b].  grid = B, block = 256.
__global__ __launch_bounds__(256) void reduce_out(
    const float* __restrict__ part3, float* __restrict__ out)
{
    const int b = blockIdx.x;
    for (int j = threadIdx.x; j < HH; j += 256) {
        float s = 0.0f;
#pragma unroll
        for (int ks = 0; ks < KS2; ++ks)
            s += part3[((size_t)ks * HH + j) * BB + b];
        out[(size_t)b * HH + j] = s;
    }
}

extern "C" void kernel_launch(void* const* d_in, const int* in_sizes, int n_in,
                              void* d_out, int out_size, void* d_ws, size_t ws_size,
                              hipStream_t stream)
{
    const float* encode_h = (const float*)d_in[0];
    const float* x_t      = (const float*)d_in[1];
    const float* h0       = (const float*)d_in[2];
    const float* c0       = (const float*)d_in[3];
    const float* W_ih     = (const float*)d_in[4];
    const float* W_hh     = (const float*)d_in[5];
    const float* b_ih     = (const float*)d_in[6];
    const float* b_hh     = (const float*)d_in[7];
    const float* W_ht2tan = (const float*)d_in[8];
    const float* W_tan2pt = (const float*)d_in[9];
    const float* W_ct2ht  = (const float*)d_in[10];
    const int*   elen     = (const int*)d_in[11];
    float* out = (float*)d_out;

    float* ws = (float*)d_ws;
    float* gates_part = ws;                                   // KS1*4096*64 = 2M
    float* yt    = gates_part + (size_t)KS1 * G4H * BB;       // 65536
    float* part2 = yt + (size_t)BB * HH;                      // KS2*1024*64 = 1M
    float* pbuf  = part2 + (size_t)KS2 * HH * BB;             // 64
    int*   lrbuf = (int*)(pbuf + BB);                         // 128 ints
    float* scbuf = pbuf + BB + 2 * BB;                        // 64*128
    float* ctbuf = scbuf + (size_t)BB * 2 * DD;               // 65536
    float* part3 = ctbuf + (size_t)BB * HH;                   // KS2*1024*64 = 1M

    // K1: gates partial GEMM  (K = 2048 | 1024 concat), grid (32,8)
    dim3 g1(G4H / 128, KS1);
    gemm_part<<<g1, 256, 0, stream>>>(x_t, EE + HH, h0, HH,
                                      W_ih, EE + HH, W_hh, HH,
                                      2048, 3072, G4H, gates_part);
    // K2: LSTM cell -> yt
    lstm_cell<<<HH / 4, 256, 0, stream>>>(gates_part, b_ih, b_hh, c0, yt);

    // K3a: t1 = yt @ W_ht2tan^T (partials), grid (8,16)
    dim3 g3(HH / 128, KS2);
    gemm_part<<<g3, 256, 0, stream>>>(yt, HH, yt, HH,
                                      W_ht2tan, HH, W_ht2tan, HH,
                                      HH, HH, HH, part2);
    // K3b: p, window bounds
    pos_kernel<<<BB, 256, 0, stream>>>(part2, W_tan2pt, elen, pbuf, lrbuf);

    // K4a: windowed raw scores, grid (64,4)
    dim3 g4a(BB, 4);
    attn_scores<<<g4a, 256, 0, stream>>>(encode_h, yt, lrbuf, scbuf);
    // K4b: softmax + gauss + ct, grid (64,4)
    dim3 g4b(BB, 4);
    attn_ct<<<g4b, 256, 0, stream>>>(encode_h, scbuf, pbuf, lrbuf, ctbuf);

    // K5: ht partials = ct @ W_ct2ht^T
    gemm_part<<<g3, 256, 0, stream>>>(ctbuf, HH, ctbuf, HH,
                                      W_ct2ht, HH, W_ct2ht, HH,
                                      HH, HH, HH, part3);
    // K6: reduce -> out
    reduce_out<<<BB, 256, 0, stream>>>(part3, out);
}

// Round 3
// 83.776 us; speedup vs baseline: 2.0031x; 1.3627x over previous
//
#include <hip/hip_runtime.h>
#include <hip/hip_bf16.h>
#include <math.h>

// Problem constants
#define BB 64
#define SS 2048
#define HH 1024
#define EE 1024
#define DD 64          // window half-size
#define G4H 4096       // 4*H
#define KS1 8          // k-splits for gates GEMM (K=3072, kchunk=384)
#define KS2 16         // k-splits for H=1024 GEMMs (kchunk=64)

__device__ __forceinline__ float sigmoidf_(float x) { return 1.0f / (1.0f + expf(-x)); }

// Register-tiled partial GEMM: part[ks][j][b] = sum_{k in chunk} Xrow(b,k)*Wrow(j,k)
// X/W are each a concat of two row-major matrices along k (split at k1len).
// Tile: 64 j x 64 b x 64 k. Thread owns acc[4 b][4 j]. grid=(Jtot/64, KS), block=256.
// LDS 35 KB -> 4 blocks/CU; FMA:ds_read = 8:1; 2-way bank aliasing only (free).
__global__ __launch_bounds__(256) void gemm_part64(
    const float* __restrict__ X1, int x1ld,
    const float* __restrict__ X2, int x2ld,
    const float* __restrict__ W1, int w1ld,
    const float* __restrict__ W2, int w2ld,
    int k1len, int Ktot, int Jtot,
    float* __restrict__ part)
{
    const int jt = blockIdx.x;        // j-tile of 64
    const int ks = blockIdx.y;
    const int KS = gridDim.y;
    const int kchunk = Ktot / KS;     // multiple of 64
    const int k0 = ks * kchunk;
    const int t  = threadIdx.x;

    const int tb = t & 15;            // b = tb + 16*bb
    const int tj = t >> 4;            // j = tj + 16*jj   (0..15)

    const int c = t & 15;             // staging k-col group (4 floats)
    const int r = t >> 4;             // staging row group

    __shared__ float Xs[64][68];      // [b][k], row stride 272B (16B aligned)
    __shared__ float Ws[64][68];      // [j][k]

    float acc[4][4];
#pragma unroll
    for (int bb = 0; bb < 4; ++bb)
#pragma unroll
        for (int jj = 0; jj < 4; ++jj) acc[bb][jj] = 0.0f;

    for (int kk = k0; kk < k0 + kchunk; kk += 64) {
        const int kg = kk + 4 * c;
#pragma unroll
        for (int i = 0; i < 4; ++i) {
            const int row = r + 16 * i;   // 0..63
            const float* xs = (kg < k1len) ? (X1 + (size_t)row * x1ld + kg)
                                           : (X2 + (size_t)row * x2ld + (kg - k1len));
            *(float4*)&Xs[row][4 * c] = *(const float4*)xs;

            const int j = jt * 64 + row;
            const float* wsrc = (kg < k1len) ? (W1 + (size_t)j * w1ld + kg)
                                             : (W2 + (size_t)j * w2ld + (kg - k1len));
            *(float4*)&Ws[row][4 * c] = *(const float4*)wsrc;
        }
        __syncthreads();

#pragma unroll
        for (int k4 = 0; k4 < 64; k4 += 4) {
            float4 xv[4], wv[4];
#pragma unroll
            for (int bb = 0; bb < 4; ++bb)
                xv[bb] = *(const float4*)&Xs[tb + 16 * bb][k4];
#pragma unroll
            for (int jj = 0; jj < 4; ++jj)
                wv[jj] = *(const float4*)&Ws[tj + 16 * jj][k4];
#pragma unroll
            for (int bb = 0; bb < 4; ++bb)
#pragma unroll
                for (int jj = 0; jj < 4; ++jj) {
                    acc[bb][jj] = fmaf(xv[bb].x, wv[jj].x, acc[bb][jj]);
                    acc[bb][jj] = fmaf(xv[bb].y, wv[jj].y, acc[bb][jj]);
                    acc[bb][jj] = fmaf(xv[bb].z, wv[jj].z, acc[bb][jj]);
                    acc[bb][jj] = fmaf(xv[bb].w, wv[jj].w, acc[bb][jj]);
                }
        }
        __syncthreads();
    }

#pragma unroll
    for (int jj = 0; jj < 4; ++jj) {
        const int j = jt * 64 + tj + 16 * jj;
#pragma unroll
        for (int bb = 0; bb < 4; ++bb)
            part[((size_t)ks * Jtot + j) * BB + (tb + 16 * bb)] = acc[bb][jj];
    }
}

// LSTM cell from gate partials. grid = H/4 = 256 blocks, block = 256.
__global__ __launch_bounds__(256) void lstm_cell(
    const float* __restrict__ part,
    const float* __restrict__ b_ih, const float* __restrict__ b_hh,
    const float* __restrict__ c0, float* __restrict__ yt)
{
    const int t = threadIdx.x;
    const int b = t & 63;
    const int h = blockIdx.x * 4 + (t >> 6);

    float g4[4];
#pragma unroll
    for (int q = 0; q < 4; ++q) {
        const int j = h + q * HH;
        float s = b_ih[j] + b_hh[j];
#pragma unroll
        for (int ks = 0; ks < KS1; ++ks)
            s += part[((size_t)ks * G4H + j) * BB + b];
        g4[q] = s;
    }
    const float ig = sigmoidf_(g4[0]);
    const float fg = sigmoidf_(g4[1]);
    const float gg = tanhf(g4[2]);
    const float og = sigmoidf_(g4[3]);
    const float c  = fg * c0[(size_t)b * HH + h] + ig * gg;
    yt[(size_t)b * HH + h] = og * tanhf(c);
}

// p_t = len * sigmoid( sum_i tanh(t1[b][i]) * v[i] ); window bounds.
// grid = B, block = 256. part2[ks][i][b]
__global__ __launch_bounds__(256) void pos_kernel(
    const float* __restrict__ part2, const float* __restrict__ v,
    const int* __restrict__ elen,
    float* __restrict__ p_out, int* __restrict__ lr_out)
{
    const int b = blockIdx.x;
    const int t = threadIdx.x;
    float acc = 0.0f;
    for (int i = t; i < HH; i += 256) {
        float s = 0.0f;
#pragma unroll
        for (int ks = 0; ks < KS2; ++ks)
            s += part2[((size_t)ks * HH + i) * BB + b];
        acc += tanhf(s) * v[i];
    }
    __shared__ float red[256];
    red[t] = acc;
    __syncthreads();
    if (t < 128) red[t] += red[t + 128];
    __syncthreads();
    if (t < 64) {
        float x = red[t] + red[t + 64];
#pragma unroll
        for (int off = 32; off; off >>= 1) x += __shfl_xor(x, off);
        if (t == 0) {
            const float pt  = sigmoidf_(x);
            const float len = (float)elen[b];
            const float p   = len * pt;
            const int   pf  = (int)floorf(p);
            const int   left  = max(0, pf - DD);
            const int   right = min(elen[b], pf + DD);
            p_out[b] = p;
            lr_out[b * 2 + 0] = left;
            lr_out[b * 2 + 1] = right;
        }
    }
}

// Windowed raw scores. grid = (B, 8), block = 256 (4 waves, 4 si each).
// Writes sc[b][0..128) with -1e30 padding beyond window.
__global__ __launch_bounds__(256) void attn_scores(
    const float* __restrict__ encode_h, const float* __restrict__ yt,
    const int* __restrict__ lr, float* __restrict__ sc_out)
{
    const int b = blockIdx.x;
    const int q = blockIdx.y;
    const int t = threadIdx.x;
    const int lane = t & 63;
    const int wv = t >> 6;

    __shared__ float yts[HH];
    *(float4*)&yts[t * 4] = *(const float4*)&yt[(size_t)b * HH + t * 4];
    const int left = lr[b * 2], right = lr[b * 2 + 1];
    const int wsize = right - left;
    __syncthreads();

#pragma unroll
    for (int rr = 0; rr < 4; ++rr) {
        const int si = q * 16 + wv * 4 + rr;
        float s = -1e30f;
        if (si < wsize) {
            const float* eh = encode_h + ((size_t)b * SS + (left + si)) * HH;
            s = 0.0f;
#pragma unroll
            for (int cc = 0; cc < 4; ++cc) {
                const int hb = cc * 256 + lane * 4;
                float4 e = *(const float4*)(eh + hb);
                s += e.x * yts[hb] + e.y * yts[hb + 1] + e.z * yts[hb + 2] + e.w * yts[hb + 3];
            }
#pragma unroll
            for (int off = 32; off; off >>= 1) s += __shfl_xor(s, off);
        }
        if (lane == 0) sc_out[b * 2 * DD + si] = s;
    }
}

// Fused softmax+gauss+ct: grid = (B, 4), block = 512.
// Threads [0..256) handle si 0..63, [256..512) handle si 64..127; LDS combine.
__global__ __launch_bounds__(512) void attn_ct(
    const float* __restrict__ encode_h, const float* __restrict__ sc,
    const float* __restrict__ p_buf, const int* __restrict__ lr,
    float* __restrict__ ct)
{
    const int b = blockIdx.x;
    const int t = threadIdx.x;
    const int lane = t & 63;
    const int hh = t & 255;
    const int half = t >> 8;
    const int h = blockIdx.y * 256 + hh;

    __shared__ float scs[2 * DD];
    __shared__ float ats[2 * DD];
    __shared__ float red[256];

    const int left = lr[b * 2];
    if (t < 2 * DD) scs[t] = sc[b * 2 * DD + t];
    __syncthreads();

    // per-wave redundant softmax stats over 128 values
    float m = fmaxf(scs[lane], scs[lane + 64]);
#pragma unroll
    for (int off = 32; off; off >>= 1) m = fmaxf(m, __shfl_xor(m, off));
    float ssum = expf(scs[lane] - m) + expf(scs[lane + 64] - m);
#pragma unroll
    for (int off = 32; off; off >>= 1) ssum += __shfl_xor(ssum, off);
    const float inv = 1.0f / ssum;

    if (t < 2 * DD) {
        const float dj = (float)(left + t) - p_buf[b];
        ats[t] = expf(scs[t] - m) * inv * expf(-(dj * dj) * (1.0f / 2048.0f));
    }
    __syncthreads();

    const float* ehb = encode_h + ((size_t)b * SS + left + half * 64) * HH + h;
    const float* atp = &ats[half * 64];
    float a0 = 0, a1 = 0, a2 = 0, a3 = 0, a4 = 0, a5 = 0, a6 = 0, a7 = 0;
#pragma unroll 2
    for (int si = 0; si < 64; si += 8) {
        a0 = fmaf(atp[si + 0], ehb[(size_t)(si + 0) * HH], a0);
        a1 = fmaf(atp[si + 1], ehb[(size_t)(si + 1) * HH], a1);
        a2 = fmaf(atp[si + 2], ehb[(size_t)(si + 2) * HH], a2);
        a3 = fmaf(atp[si + 3], ehb[(size_t)(si + 3) * HH], a3);
        a4 = fmaf(atp[si + 4], ehb[(size_t)(si + 4) * HH], a4);
        a5 = fmaf(atp[si + 5], ehb[(size_t)(si + 5) * HH], a5);
        a6 = fmaf(atp[si + 6], ehb[(size_t)(si + 6) * HH], a6);
        a7 = fmaf(atp[si + 7], ehb[(size_t)(si + 7) * HH], a7);
    }
    const float a = ((a0 + a1) + (a2 + a3)) + ((a4 + a5) + (a6 + a7));

    if (half == 1) red[hh] = a;
    __syncthreads();
    if (half == 0) ct[(size_t)b * HH + h] = a + red[hh];
}

// out[b][j] = sum_ks part3[ks][j][b].  grid = H/4 = 256, block = 256 (coalesced reads).
__global__ __launch_bounds__(256) void reduce_out(
    const float* __restrict__ part3, float* __restrict__ out)
{
    const int t = threadIdx.x;
    const int b = t & 63;
    const int j = blockIdx.x * 4 + (t >> 6);
    float s = 0.0f;
#pragma unroll
    for (int ks = 0; ks < KS2; ++ks)
        s += part3[((size_t)ks * HH + j) * BB + b];
    out[(size_t)b * HH + j] = s;
}

extern "C" void kernel_launch(void* const* d_in, const int* in_sizes, int n_in,
                              void* d_out, int out_size, void* d_ws, size_t ws_size,
                              hipStream_t stream)
{
    const float* encode_h = (const float*)d_in[0];
    const float* x_t      = (const float*)d_in[1];
    const float* h0       = (const float*)d_in[2];
    const float* c0       = (const float*)d_in[3];
    const float* W_ih     = (const float*)d_in[4];
    const float* W_hh     = (const float*)d_in[5];
    const float* b_ih     = (const float*)d_in[6];
    const float* b_hh     = (const float*)d_in[7];
    const float* W_ht2tan = (const float*)d_in[8];
    const float* W_tan2pt = (const float*)d_in[9];
    const float* W_ct2ht  = (const float*)d_in[10];
    const int*   elen     = (const int*)d_in[11];
    float* out = (float*)d_out;

    float* ws = (float*)d_ws;
    float* gates_part = ws;                                   // KS1*4096*64 = 2M
    float* yt    = gates_part + (size_t)KS1 * G4H * BB;       // 65536
    float* part2 = yt + (size_t)BB * HH;                      // KS2*1024*64 = 1M
    float* pbuf  = part2 + (size_t)KS2 * HH * BB;             // 64
    int*   lrbuf = (int*)(pbuf + BB);                         // 128 ints
    float* scbuf = pbuf + BB + 2 * BB;                        // 64*128
    float* ctbuf = scbuf + (size_t)BB * 2 * DD;               // 65536
    float* part3 = ctbuf + (size_t)BB * HH;                   // KS2*1024*64 = 1M

    // K1: gates partial GEMM  (K = 2048 | 1024 concat), grid (64,8) = 512 blocks
    dim3 g1(G4H / 64, KS1);
    gemm_part64<<<g1, 256, 0, stream>>>(x_t, EE + HH, h0, HH,
                                        W_ih, EE + HH, W_hh, HH,
                                        2048, 3072, G4H, gates_part);
    // K2: LSTM cell -> yt
    lstm_cell<<<HH / 4, 256, 0, stream>>>(gates_part, b_ih, b_hh, c0, yt);

    // K3a: t1 = yt @ W_ht2tan^T (partials), grid (16,16) = 256 blocks
    dim3 g3(HH / 64, KS2);
    gemm_part64<<<g3, 256, 0, stream>>>(yt, HH, yt, HH,
                                        W_ht2tan, HH, W_ht2tan, HH,
                                        HH, HH, HH, part2);
    // K3b: p, window bounds
    pos_kernel<<<BB, 256, 0, stream>>>(part2, W_tan2pt, elen, pbuf, lrbuf);

    // K4a: windowed raw scores, grid (64,8) = 512 blocks
    dim3 g4a(BB, 8);
    attn_scores<<<g4a, 256, 0, stream>>>(encode_h, yt, lrbuf, scbuf);
    // K4b: softmax + gauss + ct, grid (64,4), block 512
    dim3 g4b(BB, 4);
    attn_ct<<<g4b, 512, 0, stream>>>(encode_h, scbuf, pbuf, lrbuf, ctbuf);

    // K5: ht partials = ct @ W_ct2ht^T
    gemm_part64<<<g3, 256, 0, stream>>>(ctbuf, HH, ctbuf, HH,
                                        W_ct2ht, HH, W_ct2ht, HH,
                                        HH, HH, HH, part3);
    // K6: reduce -> out
    reduce_out<<<HH / 4, 256, 0, stream>>>(part3, out);
}

// Round 4
// 77.800 us; speedup vs baseline: 2.1570x; 1.0768x over previous
//
#include <hip/hip_runtime.h>
#include <hip/hip_bf16.h>
#include <math.h>

// Problem constants
#define BB 64
#define SS 2048
#define HH 1024
#define EE 1024
#define DD 64          // window half-size
#define G4H 4096       // 4*H
#define KS1 8          // k-splits for gates GEMM (K=3072, kchunk=384)
#define KS2 16         // k-splits for H=1024 GEMMs (kchunk=64)

typedef __attribute__((ext_vector_type(8))) short short8;
typedef __attribute__((ext_vector_type(4))) float floatx4;

#define MFMA_BF16(a, b, c) __builtin_amdgcn_mfma_f32_16x16x32_bf16((a), (b), (c), 0, 0, 0)

__device__ __forceinline__ float sigmoidf_(float x) { return 1.0f / (1.0f + expf(-x)); }

__device__ __forceinline__ ushort f2bf(float f) {
    return __builtin_bit_cast(ushort, __float2bfloat16(f));
}
__device__ __forceinline__ float bf2f(ushort h) {
    return __uint_as_float(((uint)h) << 16);
}

// split float4 into hi/lo bf16 pairs and store to LDS tiles (row stride 72 ushorts = 144 B)
__device__ __forceinline__ void stage_split(ushort* hbase, ushort* lbase, int row, int col, float4 v) {
    const ushort hx = f2bf(v.x), hy = f2bf(v.y), hz = f2bf(v.z), hw = f2bf(v.w);
    const float  lx = v.x - bf2f(hx), ly = v.y - bf2f(hy);
    const float  lz = v.z - bf2f(hz), lw = v.w - bf2f(hw);
    uint2 hp, lp;
    hp.x = (uint)hx | ((uint)hy << 16);
    hp.y = (uint)hz | ((uint)hw << 16);
    lp.x = (uint)f2bf(lx) | ((uint)f2bf(ly) << 16);
    lp.y = (uint)f2bf(lz) | ((uint)f2bf(lw) << 16);
    *(uint2*)(hbase + row * 72 + col) = hp;
    *(uint2*)(lbase + row * 72 + col) = lp;
}

// bf16x3 split-MFMA partial GEMM: part[ks][j][b] = sum_{k in chunk} Xrow(b,k)*Wrow(j,k)
// fp32-class accuracy via hi/lo bf16 split (hi*hi + hi*lo + lo*hi, fp32 accum).
// Tile: 64 j x 64 b x 64 k. 4 waves; wave w owns j-subtile w (16 j x 64 b).
// grid=(Jtot/64, KS), block=256. LDS 36.9 KB.
__global__ __launch_bounds__(256) void gemm_mfma(
    const float* __restrict__ X1, int x1ld,
    const float* __restrict__ X2, int x2ld,
    const float* __restrict__ W1, int w1ld,
    const float* __restrict__ W2, int w2ld,
    int k1len, int Ktot, int Jtot,
    float* __restrict__ part)
{
    const int jt = blockIdx.x;        // j-tile of 64
    const int ks = blockIdx.y;
    const int KS = gridDim.y;
    const int kchunk = Ktot / KS;     // multiple of 64
    const int k0 = ks * kchunk;
    const int t  = threadIdx.x;

    const int c = t & 15;             // staging k-col group (4 floats)
    const int r = t >> 4;             // staging row group

    const int lane = t & 63;
    const int wj   = t >> 6;          // wave id = j-subtile (0..3)
    const int rr   = lane & 15;       // A: row (j), B: col (b)
    const int kg   = lane >> 4;       // k-group: lane holds k = kg*8 .. kg*8+7

    __shared__ __align__(16) ushort Wh[64][72];
    __shared__ __align__(16) ushort Wl[64][72];
    __shared__ __align__(16) ushort Xh[64][72];
    __shared__ __align__(16) ushort Xl[64][72];

    floatx4 acc[4];
#pragma unroll
    for (int bs = 0; bs < 4; ++bs) acc[bs] = (floatx4){0.f, 0.f, 0.f, 0.f};

    for (int kk = k0; kk < k0 + kchunk; kk += 64) {
        const int kg4 = kk + 4 * c;
#pragma unroll
        for (int i = 0; i < 4; ++i) {
            const int row = r + 16 * i;   // 0..63
            const float* xs = (kg4 < k1len) ? (X1 + (size_t)row * x1ld + kg4)
                                            : (X2 + (size_t)row * x2ld + (kg4 - k1len));
            float4 xv = *(const float4*)xs;
            const int j = jt * 64 + row;
            const float* wsrc = (kg4 < k1len) ? (W1 + (size_t)j * w1ld + kg4)
                                              : (W2 + (size_t)j * w2ld + (kg4 - k1len));
            float4 wv = *(const float4*)wsrc;
            stage_split(&Xh[0][0], &Xl[0][0], row, 4 * c, xv);
            stage_split(&Wh[0][0], &Wl[0][0], row, 4 * c, wv);
        }
        __syncthreads();

        const int aoff = (wj * 16 + rr) * 72 + kg * 8;
        short8 ah[2], al[2];
        ah[0] = *(const short8*)((const void*)(&Wh[0][0] + aoff));
        ah[1] = *(const short8*)((const void*)(&Wh[0][0] + aoff + 32));
        al[0] = *(const short8*)((const void*)(&Wl[0][0] + aoff));
        al[1] = *(const short8*)((const void*)(&Wl[0][0] + aoff + 32));

#pragma unroll
        for (int bs = 0; bs < 4; ++bs) {
            const int boff = (bs * 16 + rr) * 72 + kg * 8;
#pragma unroll
            for (int kh = 0; kh < 2; ++kh) {
                short8 bh = *(const short8*)((const void*)(&Xh[0][0] + boff + kh * 32));
                short8 bl = *(const short8*)((const void*)(&Xl[0][0] + boff + kh * 32));
                acc[bs] = MFMA_BF16(ah[kh], bh, acc[bs]);   // hi*hi
                acc[bs] = MFMA_BF16(al[kh], bh, acc[bs]);   // lo*hi
                acc[bs] = MFMA_BF16(ah[kh], bl, acc[bs]);   // hi*lo
            }
        }
        __syncthreads();
    }

    // C/D layout: col = lane&15 (b), row = (lane>>4)*4 + reg (j within subtile)
#pragma unroll
    for (int bs = 0; bs < 4; ++bs) {
#pragma unroll
        for (int reg = 0; reg < 4; ++reg) {
            const int j = jt * 64 + wj * 16 + kg * 4 + reg;
            const int b = bs * 16 + rr;
            part[((size_t)ks * Jtot + j) * BB + b] = acc[bs][reg];
        }
    }
}

// LSTM cell from gate partials. grid = H/4 = 256 blocks, block = 256.
__global__ __launch_bounds__(256) void lstm_cell(
    const float* __restrict__ part,
    const float* __restrict__ b_ih, const float* __restrict__ b_hh,
    const float* __restrict__ c0, float* __restrict__ yt)
{
    const int t = threadIdx.x;
    const int b = t & 63;
    const int h = blockIdx.x * 4 + (t >> 6);

    float g4[4];
#pragma unroll
    for (int q = 0; q < 4; ++q) {
        const int j = h + q * HH;
        float s = b_ih[j] + b_hh[j];
#pragma unroll
        for (int ks = 0; ks < KS1; ++ks)
            s += part[((size_t)ks * G4H + j) * BB + b];
        g4[q] = s;
    }
    const float ig = sigmoidf_(g4[0]);
    const float fg = sigmoidf_(g4[1]);
    const float gg = tanhf(g4[2]);
    const float og = sigmoidf_(g4[3]);
    const float c  = fg * c0[(size_t)b * HH + h] + ig * gg;
    yt[(size_t)b * HH + h] = og * tanhf(c);
}

// p_t = len * sigmoid( sum_i tanh(t1[b][i]) * v[i] ); window bounds.
// grid = B, block = 256. part2[ks][i][b]
__global__ __launch_bounds__(256) void pos_kernel(
    const float* __restrict__ part2, const float* __restrict__ v,
    const int* __restrict__ elen,
    float* __restrict__ p_out, int* __restrict__ lr_out)
{
    const int b = blockIdx.x;
    const int t = threadIdx.x;
    float acc = 0.0f;
    for (int i = t; i < HH; i += 256) {
        float s = 0.0f;
#pragma unroll
        for (int ks = 0; ks < KS2; ++ks)
            s += part2[((size_t)ks * HH + i) * BB + b];
        acc += tanhf(s) * v[i];
    }
    __shared__ float red[256];
    red[t] = acc;
    __syncthreads();
    if (t < 128) red[t] += red[t + 128];
    __syncthreads();
    if (t < 64) {
        float x = red[t] + red[t + 64];
#pragma unroll
        for (int off = 32; off; off >>= 1) x += __shfl_xor(x, off);
        if (t == 0) {
            const float pt  = sigmoidf_(x);
            const float len = (float)elen[b];
            const float p   = len * pt;
            const int   pf  = (int)floorf(p);
            const int   left  = max(0, pf - DD);
            const int   right = min(elen[b], pf + DD);
            p_out[b] = p;
            lr_out[b * 2 + 0] = left;
            lr_out[b * 2 + 1] = right;
        }
    }
}

// Windowed raw scores. grid = (B, 8), block = 256 (4 waves, 4 si each).
// Writes sc[b][0..128) with -1e30 padding beyond window.
__global__ __launch_bounds__(256) void attn_scores(
    const float* __restrict__ encode_h, const float* __restrict__ yt,
    const int* __restrict__ lr, float* __restrict__ sc_out)
{
    const int b = blockIdx.x;
    const int q = blockIdx.y;
    const int t = threadIdx.x;
    const int lane = t & 63;
    const int wv = t >> 6;

    __shared__ float yts[HH];
    *(float4*)&yts[t * 4] = *(const float4*)&yt[(size_t)b * HH + t * 4];
    const int left = lr[b * 2], right = lr[b * 2 + 1];
    const int wsize = right - left;
    __syncthreads();

#pragma unroll
    for (int rr = 0; rr < 4; ++rr) {
        const int si = q * 16 + wv * 4 + rr;
        float s = -1e30f;
        if (si < wsize) {
            const float* eh = encode_h + ((size_t)b * SS + (left + si)) * HH;
            s = 0.0f;
#pragma unroll
            for (int cc = 0; cc < 4; ++cc) {
                const int hb = cc * 256 + lane * 4;
                float4 e = *(const float4*)(eh + hb);
                s += e.x * yts[hb] + e.y * yts[hb + 1] + e.z * yts[hb + 2] + e.w * yts[hb + 3];
            }
#pragma unroll
            for (int off = 32; off; off >>= 1) s += __shfl_xor(s, off);
        }
        if (lane == 0) sc_out[b * 2 * DD + si] = s;
    }
}

// Fused softmax+gauss+ct: grid = (B, 4), block = 512.
// Threads [0..256) handle si 0..63, [256..512) handle si 64..127; LDS combine.
__global__ __launch_bounds__(512) void attn_ct(
    const float* __restrict__ encode_h, const float* __restrict__ sc,
    const float* __restrict__ p_buf, const int* __restrict__ lr,
    float* __restrict__ ct)
{
    const int b = blockIdx.x;
    const int t = threadIdx.x;
    const int lane = t & 63;
    const int hh = t & 255;
    const int half = t >> 8;
    const int h = blockIdx.y * 256 + hh;

    __shared__ float scs[2 * DD];
    __shared__ float ats[2 * DD];
    __shared__ float red[256];

    const int left = lr[b * 2];
    if (t < 2 * DD) scs[t] = sc[b * 2 * DD + t];
    __syncthreads();

    // per-wave redundant softmax stats over 128 values
    float m = fmaxf(scs[lane], scs[lane + 64]);
#pragma unroll
    for (int off = 32; off; off >>= 1) m = fmaxf(m, __shfl_xor(m, off));
    float ssum = expf(scs[lane] - m) + expf(scs[lane + 64] - m);
#pragma unroll
    for (int off = 32; off; off >>= 1) ssum += __shfl_xor(ssum, off);
    const float inv = 1.0f / ssum;

    if (t < 2 * DD) {
        const float dj = (float)(left + t) - p_buf[b];
        ats[t] = expf(scs[t] - m) * inv * expf(-(dj * dj) * (1.0f / 2048.0f));
    }
    __syncthreads();

    const float* ehb = encode_h + ((size_t)b * SS + left + half * 64) * HH + h;
    const float* atp = &ats[half * 64];
    float a0 = 0, a1 = 0, a2 = 0, a3 = 0, a4 = 0, a5 = 0, a6 = 0, a7 = 0;
#pragma unroll 2
    for (int si = 0; si < 64; si += 8) {
        a0 = fmaf(atp[si + 0], ehb[(size_t)(si + 0) * HH], a0);
        a1 = fmaf(atp[si + 1], ehb[(size_t)(si + 1) * HH], a1);
        a2 = fmaf(atp[si + 2], ehb[(size_t)(si + 2) * HH], a2);
        a3 = fmaf(atp[si + 3], ehb[(size_t)(si + 3) * HH], a3);
        a4 = fmaf(atp[si + 4], ehb[(size_t)(si + 4) * HH], a4);
        a5 = fmaf(atp[si + 5], ehb[(size_t)(si + 5) * HH], a5);
        a6 = fmaf(atp[si + 6], ehb[(size_t)(si + 6) * HH], a6);
        a7 = fmaf(atp[si + 7], ehb[(size_t)(si + 7) * HH], a7);
    }
    const float a = ((a0 + a1) + (a2 + a3)) + ((a4 + a5) + (a6 + a7));

    if (half == 1) red[hh] = a;
    __syncthreads();
    if (half == 0) ct[(size_t)b * HH + h] = a + red[hh];
}

// out[b][j] = sum_ks part3[ks][j][b].  grid = H/4 = 256, block = 256 (coalesced reads).
__global__ __launch_bounds__(256) void reduce_out(
    const float* __restrict__ part3, float* __restrict__ out)
{
    const int t = threadIdx.x;
    const int b = t & 63;
    const int j = blockIdx.x * 4 + (t >> 6);
    float s = 0.0f;
#pragma unroll
    for (int ks = 0; ks < KS2; ++ks)
        s += part3[((size_t)ks * HH + j) * BB + b];
    out[(size_t)b * HH + j] = s;
}

extern "C" void kernel_launch(void* const* d_in, const int* in_sizes, int n_in,
                              void* d_out, int out_size, void* d_ws, size_t ws_size,
                              hipStream_t stream)
{
    const float* encode_h = (const float*)d_in[0];
    const float* x_t      = (const float*)d_in[1];
    const float* h0       = (const float*)d_in[2];
    const float* c0       = (const float*)d_in[3];
    const float* W_ih     = (const float*)d_in[4];
    const float* W_hh     = (const float*)d_in[5];
    const float* b_ih     = (const float*)d_in[6];
    const float* b_hh     = (const float*)d_in[7];
    const float* W_ht2tan = (const float*)d_in[8];
    const float* W_tan2pt = (const float*)d_in[9];
    const float* W_ct2ht  = (const float*)d_in[10];
    const int*   elen     = (const int*)d_in[11];
    float* out = (float*)d_out;

    float* ws = (float*)d_ws;
    float* gates_part = ws;                                   // KS1*4096*64 = 2M
    float* yt    = gates_part + (size_t)KS1 * G4H * BB;       // 65536
    float* part2 = yt + (size_t)BB * HH;                      // KS2*1024*64 = 1M
    float* pbuf  = part2 + (size_t)KS2 * HH * BB;             // 64
    int*   lrbuf = (int*)(pbuf + BB);                         // 128 ints
    float* scbuf = pbuf + BB + 2 * BB;                        // 64*128
    float* ctbuf = scbuf + (size_t)BB * 2 * DD;               // 65536
    float* part3 = ctbuf + (size_t)BB * HH;                   // KS2*1024*64 = 1M

    // K1: gates partial GEMM (K = 2048 | 1024 concat), grid (64,8) = 512 blocks
    dim3 g1(G4H / 64, KS1);
    gemm_mfma<<<g1, 256, 0, stream>>>(x_t, EE + HH, h0, HH,
                                      W_ih, EE + HH, W_hh, HH,
                                      2048, 3072, G4H, gates_part);
    // K2: LSTM cell -> yt
    lstm_cell<<<HH / 4, 256, 0, stream>>>(gates_part, b_ih, b_hh, c0, yt);

    // K3a: t1 = yt @ W_ht2tan^T (partials), grid (16,16) = 256 blocks
    dim3 g3(HH / 64, KS2);
    gemm_mfma<<<g3, 256, 0, stream>>>(yt, HH, yt, HH,
                                      W_ht2tan, HH, W_ht2tan, HH,
                                      HH, HH, HH, part2);
    // K3b: p, window bounds
    pos_kernel<<<BB, 256, 0, stream>>>(part2, W_tan2pt, elen, pbuf, lrbuf);

    // K4a: windowed raw scores, grid (64,8) = 512 blocks
    dim3 g4a(BB, 8);
    attn_scores<<<g4a, 256, 0, stream>>>(encode_h, yt, lrbuf, scbuf);
    // K4b: softmax + gauss + ct, grid (64,4), block 512
    dim3 g4b(BB, 4);
    attn_ct<<<g4b, 512, 0, stream>>>(encode_h, scbuf, pbuf, lrbuf, ctbuf);

    // K5: ht partials = ct @ W_ct2ht^T
    gemm_mfma<<<g3, 256, 0, stream>>>(ctbuf, HH, ctbuf, HH,
                                      W_ct2ht, HH, W_ct2ht, HH,
                                      HH, HH, HH, part3);
    // K6: reduce -> out
    reduce_out<<<HH / 4, 256, 0, stream>>>(part3, out);
}